// Round 4
// baseline (399.738 us; speedup 1.0000x reference)
//
#include <hip/hip_runtime.h>
#include <stdint.h>

// Problem constants (fixed by the reference)
#define C_IN   96
#define KIN    768      // 8*C
#define NOUT   192
#define EPS    1e-5f
#define NKIT   24       // K iterations (768/32)

typedef __bf16 bf16x8 __attribute__((ext_vector_type(8)));
typedef float  f32x4  __attribute__((ext_vector_type(4)));

static __device__ __forceinline__ unsigned int f2bf(float f) {
    union { float f; unsigned int u; } v; v.f = f;
    return (v.u + 0x7fffu + ((v.u >> 16) & 1u)) >> 16;   // RNE bf16, low 16 bits
}
static __device__ __forceinline__ float bf2f(unsigned int s) {
    union { unsigned int u; float f; } v; v.u = s << 16;
    return v.f;
}
// XOR swizzle on 16B granules: spreads 256B-strided access over all banks.
static __device__ __forceinline__ int swz(int a) {
    return a ^ (((a >> 8) & 7) << 4);
}

// ---------------------------------------------------------------------------
// prep_bias: bias[o] = sum_c ln_b[c]*W[o][c];  Scol[o] = sum_c bf16(W[o][c]*ln_w[c])
// (colsum folds mean subtraction: out = rs*(y_raw.W'^T - mu*S) + bias)
// ---------------------------------------------------------------------------
__global__ __launch_bounds__(256) void prep_bias(
    const float* __restrict__ W, const float* __restrict__ lnw,
    const float* __restrict__ lnb, float* __restrict__ bias,
    float* __restrict__ Scol)
{
    int o = blockIdx.x;
    int tid = threadIdx.x;
    float bpart = 0.f, spart = 0.f;
    for (int c = tid; c < KIN; c += 256) {
        float w = W[(size_t)o * KIN + c];
        spart += bf2f(f2bf(w * lnw[c]));
        bpart += w * lnb[c];
    }
    #pragma unroll
    for (int m = 32; m >= 1; m >>= 1) {
        bpart += __shfl_xor(bpart, m, 64);
        spart += __shfl_xor(spart, m, 64);
    }
    __shared__ float redb[4], reds[4];
    if ((tid & 63) == 0) { redb[tid >> 6] = bpart; reds[tid >> 6] = spart; }
    __syncthreads();
    if (tid == 0) {
        bias[o] = redb[0] + redb[1] + redb[2] + redb[3];
        Scol[o] = reds[0] + reds[1] + reds[2] + reds[3];
    }
}

// ---------------------------------------------------------------------------
// prep_swz: W' in MFMA-B-fragment order. Fragment (nt, kk) is a contiguous
// 1 KB block: lane l holds B[n = nt*16 + (l&15)][k = kk*32 + (l>>4)*8 .. +8].
// ---------------------------------------------------------------------------
__global__ __launch_bounds__(256) void prep_swz(
    const float* __restrict__ W, const float* __restrict__ lnw,
    unsigned short* __restrict__ Wsw)
{
    const int nt = blockIdx.x;               // 0..11
    for (int s = threadIdx.x; s < NKIT * 64; s += 256) {
        const int kk = s >> 6;
        const int l  = s & 63;
        const int row = nt * 16 + (l & 15);
        const int k0  = kk * 32 + (l >> 4) * 8;
        const float* src = W + (size_t)row * KIN + k0;
        unsigned int p[4];
        #pragma unroll
        for (int j = 0; j < 4; ++j) {
            float a = src[2 * j]     * lnw[k0 + 2 * j];
            float b = src[2 * j + 1] * lnw[k0 + 2 * j + 1];
            p[j] = f2bf(a) | (f2bf(b) << 16);
        }
        *(uint4*)&Wsw[(size_t)((nt * NKIT + kk) * 64 + l) * 8] =
            make_uint4(p[0], p[1], p[2], p[3]);
    }
}

// ---------------------------------------------------------------------------
// repack_kernel: x (fp32, row-linear) -> ytile (bf16, A-fragment order) + stats.
// Block = one 16-token M-tile. Source = 4 contiguous 12 KB rows (one per wave).
// LDS 24.6 KB -> 6 blocks/CU (24 waves/CU). No gather: reads are pure streams.
// ---------------------------------------------------------------------------
__global__ __launch_bounds__(256) void repack_kernel(
    const float* __restrict__ x, unsigned short* __restrict__ yt,
    float2* __restrict__ stats)
{
    __shared__ unsigned char tile[24576 + 64];

    const int tid = threadIdx.x;
    const int mt  = blockIdx.x;                 // M-tile = 16 tokens
    const int b  = mt >> 11;
    const int d  = (mt >> 6) & 31;
    const int h  = (mt >> 1) & 31;
    const int wh = mt & 1;

    const int r = tid >> 6;                     // wave = source row (s0,s1)
    const int l = tid & 63;
    const int s0 = r >> 1, s1 = r & 1;
    const float* src = x +
        (((size_t)(b * 64 + 2 * d + s0) * 64 + (2 * h + s1)) * 64 + wh * 32) * C_IN
        + l * 4;

    // ---- linear load: 12 float4/thread, wave reads 1 KB contiguous per step
    float4 v[12];
    #pragma unroll
    for (int it = 0; it < 12; ++it)
        v[it] = *(const float4*)(src + it * 256);
    __builtin_amdgcn_sched_barrier(0);

    // ---- convert + scatter into fragment-ordered LDS (swizzled) -------------
    #pragma unroll
    for (int it = 0; it < 12; ++it) {
        const int p  = it * 256 + l * 4;        // float index within the row
        const int t5 = p >> 5;
        const int xw = (t5 * 171) >> 9;         // p / 96
        const int c  = p - xw * 96;
        const int m  = xw >> 1;                 // token within tile
        const int k  = (r * 2 + (xw & 1)) * 96 + c;   // g = 4*s0+2*s1+s2
        const int kk = k >> 5, quad = (k >> 3) & 3, sub = (k & 4) << 1;
        const int addr = ((kk << 6) + m + (quad << 4)) * 16 + sub;
        uint2 pk;
        pk.x = f2bf(v[it].x) | (f2bf(v[it].y) << 16);
        pk.y = f2bf(v[it].z) | (f2bf(v[it].w) << 16);
        *(uint2*)(tile + swz(addr)) = pk;
    }
    __syncthreads();

    // ---- linear write-out: M-tile block is contiguous 24 KB -----------------
    char* dst = (char*)yt + (size_t)mt * 24576;
    #pragma unroll
    for (int s = 0; s < 6; ++s) {
        const int lin = s * 4096 + tid * 16;
        *(uint4*)(dst + lin) = *(const uint4*)(tile + swz(lin));
    }

    // ---- per-token stats from the bf16 tile (16 threads/token) --------------
    {
        const int m = tid >> 4, j = tid & 15;
        float sum = 0.f, sq = 0.f;
        #pragma unroll
        for (int e6 = 0; e6 < 6; ++e6) {
            const int e  = j + e6 * 16;         // 0..95 = (kk, quad)
            const int kk = e >> 2, quad = e & 3;
            const int a  = ((kk << 6) + m + (quad << 4)) * 16;
            uint4 u = *(const uint4*)(tile + swz(a));
            const unsigned int w[4] = {u.x, u.y, u.z, u.w};
            #pragma unroll
            for (int q = 0; q < 4; ++q) {
                float lo = bf2f(w[q] & 0xffffu);
                float hi = bf2f(w[q] >> 16);
                sum += lo + hi;
                sq  += lo * lo + hi * hi;
            }
        }
        #pragma unroll
        for (int msk = 1; msk <= 8; msk <<= 1) {
            sum += __shfl_xor(sum, msk, 16);
            sq  += __shfl_xor(sq,  msk, 16);
        }
        if (j == 0) {
            float mean = sum * (1.f / 768.f);
            float var  = sq * (1.f / 768.f) - mean * mean;
            stats[mt * 16 + m] = make_float2(mean, rsqrtf(var + EPS));
        }
    }
}

// ---------------------------------------------------------------------------
// gemm_kernel: out = rs*(y.W'^T - mu*S) + bias. No LDS, no barriers.
// Wave = 2 M-tiles x 96 cols; A-fragments are coalesced 1 KB global loads.
// ---------------------------------------------------------------------------
__global__ __launch_bounds__(256, 3) void gemm_kernel(
    const unsigned short* __restrict__ yt, const unsigned short* __restrict__ Wsw,
    const float* __restrict__ bias, const float* __restrict__ Scol,
    const float2* __restrict__ stats, float* __restrict__ out)
{
    const int tid  = threadIdx.x;
    const int wv   = tid >> 6;
    const int l    = tid & 63;
    const int l15  = l & 15;
    const int quad = l >> 4;
    const int nh   = wv & 1;                     // N-half: cols [nh*96, nh*96+96)
    const int mt0  = blockIdx.x * 4 + (wv >> 1) * 2;   // first of the M-tile pair

    const char* aptr0 = (const char*)yt + (size_t)mt0 * 24576 + l * 16;
    const char* aptr1 = aptr0 + 24576;
    const char* bptr  = (const char*)Wsw + (size_t)nh * 6 * NKIT * 1024 + l * 16;

    f32x4 acc[2][6];
    #pragma unroll
    for (int mi = 0; mi < 2; ++mi)
        #pragma unroll
        for (int nt = 0; nt < 6; ++nt)
            acc[mi][nt] = (f32x4){0.f, 0.f, 0.f, 0.f};

    // depth-2 pipeline
    bf16x8 A[2][2], Bv[2][6];
    #pragma unroll
    for (int p = 0; p < 2; ++p) {
        A[p][0] = *(const bf16x8*)(aptr0 + p * 1024);
        A[p][1] = *(const bf16x8*)(aptr1 + p * 1024);
        #pragma unroll
        for (int nt = 0; nt < 6; ++nt)
            Bv[p][nt] = *(const bf16x8*)(bptr + (size_t)(nt * NKIT + p) * 1024);
    }
    #pragma unroll
    for (int kk = 0; kk < NKIT; ++kk) {
        const int c = kk & 1;
        bf16x8 nA0, nA1, nB[6];
        if (kk < NKIT - 2) {
            const int k2 = kk + 2;
            nA0 = *(const bf16x8*)(aptr0 + k2 * 1024);
            nA1 = *(const bf16x8*)(aptr1 + k2 * 1024);
            #pragma unroll
            for (int nt = 0; nt < 6; ++nt)
                nB[nt] = *(const bf16x8*)(bptr + (size_t)(nt * NKIT + k2) * 1024);
        }
        #pragma unroll
        for (int nt = 0; nt < 6; ++nt) {
            acc[0][nt] = __builtin_amdgcn_mfma_f32_16x16x32_bf16(A[c][0], Bv[c][nt], acc[0][nt], 0, 0, 0);
            acc[1][nt] = __builtin_amdgcn_mfma_f32_16x16x32_bf16(A[c][1], Bv[c][nt], acc[1][nt], 0, 0, 0);
        }
        if (kk < NKIT - 2) {
            A[c][0] = nA0; A[c][1] = nA1;
            #pragma unroll
            for (int nt = 0; nt < 6; ++nt) Bv[c][nt] = nB[nt];
        }
    }

    // ---- epilogue ----------------------------------------------------------
    float2 st[2][4];
    #pragma unroll
    for (int mi = 0; mi < 2; ++mi)
        #pragma unroll
        for (int rr = 0; rr < 4; ++rr)
            st[mi][rr] = stats[(mt0 + mi) * 16 + quad * 4 + rr];

    #pragma unroll
    for (int nt = 0; nt < 6; ++nt) {
        const int col = nh * 96 + nt * 16 + l15;
        const float S = Scol[col];
        const float bc = bias[col];
        #pragma unroll
        for (int mi = 0; mi < 2; ++mi) {
            #pragma unroll
            for (int rr = 0; rr < 4; ++rr) {
                const int t = (mt0 + mi) * 16 + quad * 4 + rr;
                const float mu = st[mi][rr].x, rs = st[mi][rr].y;
                out[(size_t)t * NOUT + col] = rs * acc[mi][nt][rr] - rs * mu * S + bc;
            }
        }
    }
}

// ---------------------------------------------------------------------------
extern "C" void kernel_launch(void* const* d_in, const int* in_sizes, int n_in,
                              void* d_out, int out_size, void* d_ws, size_t ws_size,
                              hipStream_t stream) {
    const float* x   = (const float*)d_in[0];
    const float* lnw = (const float*)d_in[1];
    const float* lnb = (const float*)d_in[2];
    const float* W   = (const float*)d_in[3];
    float* out = (float*)d_out;

    // workspace layout
    char* ws = (char*)d_ws;
    unsigned short* Wsw  = (unsigned short*)ws;                     // 294912 B
    float* bias          = (float*)(ws + 294912);                   // 768 B
    float* Scol          = (float*)(ws + 295680);                   // 768 B
    float2* stats        = (float2*)(ws + 296448);                  // 524288 B
    unsigned short* yt   = (unsigned short*)(ws + 1048576);         // 100663296 B

    prep_bias<<<NOUT, 256, 0, stream>>>(W, lnw, lnb, bias, Scol);
    prep_swz<<<12, 256, 0, stream>>>(W, lnw, Wsw);
    repack_kernel<<<4096, 256, 0, stream>>>(x, yt, stats);
    gemm_kernel<<<1024, 256, 0, stream>>>(yt, Wsw, bias, Scol, stats, out);
}

// Round 6
// 332.538 us; speedup vs baseline: 1.2021x; 1.2021x over previous
//
#include <hip/hip_runtime.h>
#include <stdint.h>

// Problem constants (fixed by the reference)
#define C_IN   96
#define KIN    768      // 8*C
#define NOUT   192
#define EPS    1e-5f
#define NKIT   24       // K iterations (768/32)

typedef __bf16 bf16x8 __attribute__((ext_vector_type(8)));
typedef float  f32x4  __attribute__((ext_vector_type(4)));

static __device__ __forceinline__ unsigned int f2bf(float f) {
    union { float f; unsigned int u; } v; v.f = f;
    return (v.u + 0x7fffu + ((v.u >> 16) & 1u)) >> 16;   // RNE bf16, low 16 bits
}
static __device__ __forceinline__ float bf2f(unsigned int s) {
    union { unsigned int u; float f; } v; v.u = s << 16;
    return v.f;
}
// XOR swizzle on 16B granules within 2KB windows (verified in R4's repack:
// write-side and read-side use the same mapping; sub-16B offsets commute).
static __device__ __forceinline__ int swz(int a) {
    return a ^ (((a >> 8) & 7) << 4);
}

// ---------------------------------------------------------------------------
// prep_bias: bias[o] = sum_c ln_b[c]*W[o][c];  Scol[o] = sum_c bf16(W[o][c]*ln_w[c])
// (colsum folds mean subtraction: out = rs*(y_raw.W'^T - mu*S) + bias)
// ---------------------------------------------------------------------------
__global__ __launch_bounds__(256) void prep_bias(
    const float* __restrict__ W, const float* __restrict__ lnw,
    const float* __restrict__ lnb, float* __restrict__ bias,
    float* __restrict__ Scol)
{
    int o = blockIdx.x;
    int tid = threadIdx.x;
    float bpart = 0.f, spart = 0.f;
    for (int c = tid; c < KIN; c += 256) {
        float w = W[(size_t)o * KIN + c];
        spart += bf2f(f2bf(w * lnw[c]));
        bpart += w * lnb[c];
    }
    #pragma unroll
    for (int m = 32; m >= 1; m >>= 1) {
        bpart += __shfl_xor(bpart, m, 64);
        spart += __shfl_xor(spart, m, 64);
    }
    __shared__ float redb[4], reds[4];
    if ((tid & 63) == 0) { redb[tid >> 6] = bpart; reds[tid >> 6] = spart; }
    __syncthreads();
    if (tid == 0) {
        bias[o] = redb[0] + redb[1] + redb[2] + redb[3];
        Scol[o] = reds[0] + reds[1] + reds[2] + reds[3];
    }
}

// ---------------------------------------------------------------------------
// prep_swz: W' in MFMA-B-fragment order. Fragment (nt, kk) is a contiguous
// 1 KB block: lane l holds B[n = nt*16 + (l&15)][k = kk*32 + (l>>4)*8 .. +8].
// ---------------------------------------------------------------------------
__global__ __launch_bounds__(256) void prep_swz(
    const float* __restrict__ W, const float* __restrict__ lnw,
    unsigned short* __restrict__ Wsw)
{
    const int nt = blockIdx.x;               // 0..11
    for (int s = threadIdx.x; s < NKIT * 64; s += 256) {
        const int kk = s >> 6;
        const int l  = s & 63;
        const int row = nt * 16 + (l & 15);
        const int k0  = kk * 32 + (l >> 4) * 8;
        const float* src = W + (size_t)row * KIN + k0;
        unsigned int p[4];
        #pragma unroll
        for (int j = 0; j < 4; ++j) {
            float a = src[2 * j]     * lnw[k0 + 2 * j];
            float b = src[2 * j + 1] * lnw[k0 + 2 * j + 1];
            p[j] = f2bf(a) | (f2bf(b) << 16);
        }
        *(uint4*)&Wsw[(size_t)((nt * NKIT + kk) * 64 + l) * 8] =
            make_uint4(p[0], p[1], p[2], p[3]);
    }
}

// ---------------------------------------------------------------------------
// merge_kernel: ONE PASS, linear reads, high occupancy.
// Block = 16 tokens (b, d, h, wh). Wave r reads the contiguous 12 KB source
// row (s0,s1)=r (lane-contiguous 1 KB wave-loads), converts to bf16 and
// scatters into a 24 KB A-fragment LDS tile (R4-verified index math + swz).
// Then stats (bf16-consistent) and the MFMA GEMM with LN folded in the
// epilogue. LDS 24.7 KB + launch_bounds(256,6) -> 6 blocks / 24 waves per CU.
// ---------------------------------------------------------------------------
__global__ __launch_bounds__(256, 6) void merge_kernel(
    const float* __restrict__ x, const unsigned short* __restrict__ Wsw,
    const float* __restrict__ bias, const float* __restrict__ Scol,
    float* __restrict__ out)
{
    __shared__ unsigned char tile[24576 + 64];   // bf16 A-fragment tile
    __shared__ float muL[16], rsL[16];

    const int tid = threadIdx.x;
    const int mt  = blockIdx.x;                 // M-tile = 16 tokens
    const int b   = mt >> 11;
    const int d   = (mt >> 6) & 31;
    const int h   = (mt >> 1) & 31;
    const int wh  = mt & 1;

    const int r = tid >> 6;                     // wave = source row (s0,s1)
    const int l = tid & 63;
    const int s0 = r >> 1, s1 = r & 1;
    const float* src = x +
        (((size_t)(b * 64 + 2 * d + s0) * 64 + (2 * h + s1)) * 64 + wh * 32) * C_IN
        + l * 4;

    // ---- Phase 1: linear load, 12 x (1 KB contiguous per wave-inst) ---------
    float4 v[12];
    #pragma unroll
    for (int it = 0; it < 12; ++it)
        v[it] = *(const float4*)(src + it * 256);
    __builtin_amdgcn_sched_barrier(0);

    // ---- convert + scatter into fragment-ordered bf16 LDS (swizzled) --------
    #pragma unroll
    for (int it = 0; it < 12; ++it) {
        const int p  = it * 256 + l * 4;        // float index within the row
        const int t5 = p >> 5;
        const int xw = (t5 * 171) >> 9;         // p / 96
        const int c  = p - xw * 96;
        const int m  = xw >> 1;                 // token within tile
        const int k  = (r * 2 + (xw & 1)) * 96 + c;   // g = 4*s0+2*s1+s2
        const int kk = k >> 5, quad = (k >> 3) & 3, sub = (k & 4) << 1;
        const int addr = ((kk << 6) + m + (quad << 4)) * 16 + sub;
        uint2 pk;
        pk.x = f2bf(v[it].x) | (f2bf(v[it].y) << 16);
        pk.y = f2bf(v[it].z) | (f2bf(v[it].w) << 16);
        *(uint2*)(tile + swz(addr)) = pk;
    }
    __syncthreads();

    // ---- Phase 2: per-token stats from the bf16 tile (16 threads/token) -----
    {
        const int sm = tid >> 4, j = tid & 15;
        float sum = 0.f, sq = 0.f;
        #pragma unroll
        for (int t = 0; t < 6; ++t) {
            const int e  = j + t * 16;          // 0..95 enumerates (kk, quad)
            const int akk = e >> 2, aq = e & 3;
            const int a  = ((akk << 6) + sm + (aq << 4)) * 16;
            uint4 u = *(const uint4*)(tile + swz(a));
            const unsigned int w[4] = {u.x, u.y, u.z, u.w};
            #pragma unroll
            for (int q = 0; q < 4; ++q) {
                float lo = bf2f(w[q] & 0xffffu);
                float hi = bf2f(w[q] >> 16);
                sum += lo + hi;
                sq  += lo * lo + hi * hi;
            }
        }
        #pragma unroll
        for (int msk = 1; msk <= 8; msk <<= 1) {
            sum += __shfl_xor(sum, msk, 16);
            sq  += __shfl_xor(sq,  msk, 16);
        }
        if (j == 0) {
            float mean = sum * (1.f / 768.f);
            float var  = sq * (1.f / 768.f) - mean * mean;
            muL[sm] = mean;
            rsL[sm] = rsqrtf(var + EPS);
        }
    }
    __syncthreads();

    // ---- Phase 3: GEMM. Wave wv -> cols [wv*48, wv*48+48) (3 n-tiles) -------
    const int m15 = l & 15;
    const int qd  = l >> 4;
    const char* bp = (const char*)Wsw + ((size_t)(3 * r) * NKIT * 64 + l) * 16;

    f32x4 acc0 = {0.f, 0.f, 0.f, 0.f};
    f32x4 acc1 = {0.f, 0.f, 0.f, 0.f};
    f32x4 acc2 = {0.f, 0.f, 0.f, 0.f};

    // depth-2 pipeline on A (LDS) + B (L2-hot global)
    bf16x8 A[2], B0[2], B1[2], B2[2];
    #pragma unroll
    for (int p = 0; p < 2; ++p) {
        A[p]  = *(const bf16x8*)(tile + swz((p * 64 + l) * 16));
        B0[p] = *(const bf16x8*)(bp + (size_t)p * 1024);
        B1[p] = *(const bf16x8*)(bp + 24576 + (size_t)p * 1024);
        B2[p] = *(const bf16x8*)(bp + 49152 + (size_t)p * 1024);
    }
    #pragma unroll
    for (int kk = 0; kk < NKIT; ++kk) {
        const int c = kk & 1;
        bf16x8 nA, nB0, nB1, nB2;
        if (kk < NKIT - 2) {
            const int k2 = kk + 2;
            nA  = *(const bf16x8*)(tile + swz((k2 * 64 + l) * 16));
            nB0 = *(const bf16x8*)(bp + (size_t)k2 * 1024);
            nB1 = *(const bf16x8*)(bp + 24576 + (size_t)k2 * 1024);
            nB2 = *(const bf16x8*)(bp + 49152 + (size_t)k2 * 1024);
        }
        acc0 = __builtin_amdgcn_mfma_f32_16x16x32_bf16(A[c], B0[c], acc0, 0, 0, 0);
        acc1 = __builtin_amdgcn_mfma_f32_16x16x32_bf16(A[c], B1[c], acc1, 0, 0, 0);
        acc2 = __builtin_amdgcn_mfma_f32_16x16x32_bf16(A[c], B2[c], acc2, 0, 0, 0);
        if (kk < NKIT - 2) { A[c] = nA; B0[c] = nB0; B1[c] = nB1; B2[c] = nB2; }
    }

    // ---- Epilogue: out = rs*(dot - mu*S) + bias -----------------------------
    const int nb = r * 48;
    #pragma unroll
    for (int nt = 0; nt < 3; ++nt) {
        const int col = nb + nt * 16 + m15;
        const float S  = Scol[col];
        const float bc = bias[col];
        const f32x4 av = (nt == 0) ? acc0 : (nt == 1) ? acc1 : acc2;
        #pragma unroll
        for (int rr = 0; rr < 4; ++rr) {
            const int row = qd * 4 + rr;
            const float rs = rsL[row], mu = muL[row];
            out[((size_t)mt * 16 + row) * NOUT + col] = rs * av[rr] - rs * mu * S + bc;
        }
    }
}

// ---------------------------------------------------------------------------
extern "C" void kernel_launch(void* const* d_in, const int* in_sizes, int n_in,
                              void* d_out, int out_size, void* d_ws, size_t ws_size,
                              hipStream_t stream) {
    const float* x   = (const float*)d_in[0];
    const float* lnw = (const float*)d_in[1];
    const float* lnb = (const float*)d_in[2];
    const float* W   = (const float*)d_in[3];
    float* out = (float*)d_out;

    char* ws = (char*)d_ws;
    unsigned short* Wsw = (unsigned short*)ws;            // 294912 B
    float* bias         = (float*)(ws + 294912);          // 768 B
    float* Scol         = (float*)(ws + 295680);          // 768 B

    prep_bias<<<NOUT, 256, 0, stream>>>(W, lnw, lnb, bias, Scol);
    prep_swz<<<12, 256, 0, stream>>>(W, lnw, Wsw);
    merge_kernel<<<4096, 256, 0, stream>>>(x, Wsw, bias, Scol, out);
}